// Round 1
// baseline (279.553 us; speedup 1.0000x reference)
//
#include <hip/hip_runtime.h>

// ---------------------------------------------------------------------------
// Fused 2-layer LSTM, N=8192, T=28, I=28, H=128, + final [128->10] linear.
// One block = 32 samples through all 28 timesteps of both layers.
// grid = 256 blocks x 512 threads (8 waves) -> exactly 1 block / CU.
//
// Weights: w_hh0, w_hh1, w_ih0 persist in VGPRs as MFMA B-fragments
//          (loaded once from the packed d_ws image); w_ih1 persists in LDS.
// All MFMA fragments use a lane-major tiled layout:
//   [k-chunk][n-tile][lane][8 bf16]  (16 B per lane) so every frag access is
//   ds_read_b128 / global_load_dwordx4 at base + lane*16 (conflict-free).
// ---------------------------------------------------------------------------

typedef short  short8   __attribute__((ext_vector_type(8)));
typedef float  float4_t __attribute__((ext_vector_type(4)));

#define WIH1_OFF 0        // 131072 B : w_ih1, persistent in LDS
#define H0_OFF   131072   //   8192 B : h0 tile, A-frag tiled bf16
#define H1_OFF   139264   //   8192 B : h1 tile
#define X_OFF    147456   //   2048 B : x_t tile (k padded 28->32 with zeros)
#define SMEM_SZ  149504   // <= 163840 addressable LDS on gfx950

__device__ __forceinline__ unsigned short bf16r(float v) {
  union { float f; unsigned u; } x; x.f = v;
  unsigned r = x.u + 0x7fffu + ((x.u >> 16) & 1u);   // round-to-nearest-even
  return (unsigned short)(r >> 16);
}
__device__ __forceinline__ float bf2f(unsigned short b) {
  union { unsigned u; float f; } x; x.u = ((unsigned)b) << 16;
  return x.f;
}
__device__ __forceinline__ float sigf(float x)  { return 1.0f / (1.0f + __expf(-x)); }
__device__ __forceinline__ float tanhfast(float x) { return 1.0f - 2.0f / (__expf(2.0f * x) + 1.0f); }

// ---------------------------------------------------------------------------
// Prologue: pack weights (fp32 -> bf16) into MFMA B-frag tiled layout in ws.
// ws (unsigned short units):
//   [0      ,16384) : w_ih0  [1 kc][32 tiles][64 lanes][8]  (k padded to 32)
//   [16384  ,81920) : w_hh0  [4 kc][32 tiles][64][8]
//   [81920 ,147456) : w_ih1  [4 kc][32][64][8]
//   [147456,212992) : w_hh1  [4 kc][32][64][8]
// element (tile,lane,j): row = tile*16 + (lane&15), k = kc*32 + (lane>>4)*8 + j
// ---------------------------------------------------------------------------
__global__ void pack_weights(const float* __restrict__ wih0, const float* __restrict__ whh0,
                             const float* __restrict__ wih1, const float* __restrict__ whh1,
                             unsigned short* __restrict__ dst)
{
  int e = blockIdx.x * 256 + threadIdx.x;
  const float* src; int K; int i;
  if      (e < 16384)  { src = wih0; K = 28;  i = e;          }
  else if (e < 81920)  { src = whh0; K = 128; i = e - 16384;  }
  else if (e < 147456) { src = wih1; K = 128; i = e - 81920;  }
  else if (e < 212992) { src = whh1; K = 128; i = e - 147456; }
  else return;
  int j = i & 7, lane = (i >> 3) & 63, tile = (i >> 9) & 31, kc = i >> 14;
  int row = tile * 16 + (lane & 15);
  int k = kc * 32 + ((lane >> 4) << 3) + j;
  float v = (k < K) ? src[row * K + k] : 0.0f;
  dst[e] = bf16r(v);
}

// ---------------------------------------------------------------------------
// Main fused kernel.
// ---------------------------------------------------------------------------
__global__ __launch_bounds__(512, 2)
void lstm_fused(const float* __restrict__ xg,
                const unsigned short* __restrict__ wpack,
                const float* __restrict__ bih0, const float* __restrict__ bhh0,
                const float* __restrict__ bih1, const float* __restrict__ bhh1,
                const float* __restrict__ wout, const float* __restrict__ bout,
                float* __restrict__ out)
{
  __shared__ __align__(16) char smem[SMEM_SZ];

  const int tid  = threadIdx.x;
  const int lane = tid & 63;
  const int wave = tid >> 6;          // 0..7, owns h-dims [wave*16, wave*16+16)
  const int q    = lane >> 4;         // quad: acc rows q*4 .. q*4+3
  const int mcol = lane & 15;         // acc col = h-dim within wave slice
  const int n0   = blockIdx.x * 32;   // batch tile base

  const short8* wp = (const short8*)wpack;

  // ---- persistent weight fragments in registers --------------------------
  short8 wih0[4], whh0[4][4], whh1[4][4];          // [g] / [kc][g]
#pragma unroll
  for (int g = 0; g < 4; ++g)
    wih0[g] = wp[(g * 8 + wave) * 64 + lane];
#pragma unroll
  for (int kc = 0; kc < 4; ++kc)
#pragma unroll
    for (int g = 0; g < 4; ++g) {
      whh0[kc][g] = wp[ 2048 + (kc * 32 + g * 8 + wave) * 64 + lane];
      whh1[kc][g] = wp[18432 + (kc * 32 + g * 8 + wave) * 64 + lane];
    }

  // ---- persistent w_ih1 in LDS (131072 B) --------------------------------
  {
    short8* dstp = (short8*)smem;
#pragma unroll
    for (int rr = 0; rr < 16; ++rr)
      dstp[rr * 512 + tid] = wp[10240 + rr * 512 + tid];
  }

  // ---- biases (per-lane, gate g, dim = wave*16+mcol) ---------------------
  float bias0[4], bias1[4];
  {
    const int d = wave * 16 + mcol;
#pragma unroll
    for (int g = 0; g < 4; ++g) {
      bias0[g] = bih0[g * 128 + d] + bhh0[g * 128 + d];
      bias1[g] = bih1[g * 128 + d] + bhh1[g * 128 + d];
    }
  }

  // ---- zero h0/h1/x regions (also creates the k=28..31 zero pad of x) ----
  {
    int* hz = (int*)(smem + H0_OFF);
#pragma unroll
    for (int rr = 0; rr < 9; ++rr) hz[rr * 512 + tid] = 0;  // 18432 B
  }

  // ---- x_t staging: fp32 global -> bf16 A-frag tile in LDS ---------------
  auto stage_x = [&](int t) {
    if (tid < 448) {
      int s  = tid / 14;
      int kk = tid - s * 14;
      int k  = kk * 2;
      const float* xs = xg + (size_t)(n0 + s) * 784 + t * 28 + k;
      float v0 = xs[0], v1 = xs[1];
      unsigned u = (unsigned)bf16r(v0) | ((unsigned)bf16r(v1) << 16);
      int mt = s >> 4;
      int addr = X_OFF + mt * 1024 + ((((k >> 3) & 3) << 4) + (s & 15)) * 16 + (k & 7) * 2;
      *(unsigned*)(smem + addr) = u;
    }
  };
  stage_x(0);
  __syncthreads();   // weights in LDS, x_0 staged, h zeroed

  const short8* H0f = (const short8*)(smem + H0_OFF);
  const short8* H1f = (const short8*)(smem + H1_OFF);
  const short8* Xf  = (const short8*)(smem + X_OFF);
  const short8* W1f = (const short8*)(smem + WIH1_OFF);

  // per-lane constant part of the h-write address (A-frag tiled position of
  // element (s, d) with d = wave*16+mcol):
  const int kc_d   = wave >> 1;
  const int sub    = ((wave & 1) << 1) | (mcol >> 3);
  const int hconst = kc_d * 1024 + sub * 256 + q * 64 + (mcol & 7) * 2;

  float c0[2][4] = {{0.f,0.f,0.f,0.f},{0.f,0.f,0.f,0.f}};
  float c1[2][4] = {{0.f,0.f,0.f,0.f},{0.f,0.f,0.f,0.f}};

#pragma unroll 1
  for (int t = 0; t < 28; ++t) {
    float4_t acc[2][4];
    unsigned short hb[2][4];

    // ================= LAYER 0 : gates = b0 + x_t@Wih0^T + h0@Whh0^T =====
#pragma unroll
    for (int mt = 0; mt < 2; ++mt)
#pragma unroll
      for (int g = 0; g < 4; ++g)
        acc[mt][g] = (float4_t){bias0[g], bias0[g], bias0[g], bias0[g]};
#pragma unroll
    for (int mt = 0; mt < 2; ++mt) {
      short8 xf = Xf[mt * 64 + lane];
#pragma unroll
      for (int g = 0; g < 4; ++g)
        acc[mt][g] = __builtin_amdgcn_mfma_f32_16x16x32_bf16(xf, wih0[g], acc[mt][g], 0, 0, 0);
    }
#pragma unroll
    for (int kc = 0; kc < 4; ++kc)
#pragma unroll
      for (int mt = 0; mt < 2; ++mt) {
        short8 hf = H0f[(mt * 4 + kc) * 64 + lane];
#pragma unroll
        for (int g = 0; g < 4; ++g)
          acc[mt][g] = __builtin_amdgcn_mfma_f32_16x16x32_bf16(hf, whh0[kc][g], acc[mt][g], 0, 0, 0);
      }
    // activations (gate order i,f,g,o); c stays in registers
#pragma unroll
    for (int mt = 0; mt < 2; ++mt)
#pragma unroll
      for (int r = 0; r < 4; ++r) {
        float c = sigf(acc[mt][1][r]) * c0[mt][r] + sigf(acc[mt][0][r]) * tanhfast(acc[mt][2][r]);
        c0[mt][r] = c;
        hb[mt][r] = bf16r(sigf(acc[mt][3][r]) * tanhfast(c));
      }
    __syncthreads();   // B1: all reads of h0_{t-1} and x_t are done
#pragma unroll
    for (int mt = 0; mt < 2; ++mt)
#pragma unroll
      for (int r = 0; r < 4; ++r)
        *(unsigned short*)(smem + H0_OFF + mt * 4096 + r * 16 + hconst) = hb[mt][r];
    __syncthreads();   // B1b: h0_t visible to all waves

    // ================= LAYER 1 : gates = b1 + h0_t@Wih1^T + h1@Whh1^T ====
#pragma unroll
    for (int mt = 0; mt < 2; ++mt)
#pragma unroll
      for (int g = 0; g < 4; ++g)
        acc[mt][g] = (float4_t){bias1[g], bias1[g], bias1[g], bias1[g]};
#pragma unroll
    for (int kc = 0; kc < 4; ++kc) {
      short8 wf[4];
#pragma unroll
      for (int g = 0; g < 4; ++g)
        wf[g] = W1f[(kc * 32 + g * 8 + wave) * 64 + lane];
#pragma unroll
      for (int mt = 0; mt < 2; ++mt) {
        short8 hf = H0f[(mt * 4 + kc) * 64 + lane];
#pragma unroll
        for (int g = 0; g < 4; ++g)
          acc[mt][g] = __builtin_amdgcn_mfma_f32_16x16x32_bf16(hf, wf[g], acc[mt][g], 0, 0, 0);
      }
    }
#pragma unroll
    for (int kc = 0; kc < 4; ++kc)
#pragma unroll
      for (int mt = 0; mt < 2; ++mt) {
        short8 hf = H1f[(mt * 4 + kc) * 64 + lane];
#pragma unroll
        for (int g = 0; g < 4; ++g)
          acc[mt][g] = __builtin_amdgcn_mfma_f32_16x16x32_bf16(hf, whh1[kc][g], acc[mt][g], 0, 0, 0);
      }
    // stage x_{t+1} (x_t reads finished before B1; visible after B2)
    if (t < 27) stage_x(t + 1);
    // activations
#pragma unroll
    for (int mt = 0; mt < 2; ++mt)
#pragma unroll
      for (int r = 0; r < 4; ++r) {
        float c = sigf(acc[mt][1][r]) * c1[mt][r] + sigf(acc[mt][0][r]) * tanhfast(acc[mt][2][r]);
        c1[mt][r] = c;
        hb[mt][r] = bf16r(sigf(acc[mt][3][r]) * tanhfast(c));
      }
    __syncthreads();   // B2: all reads of h1_{t-1} done; x_{t+1} visible next
#pragma unroll
    for (int mt = 0; mt < 2; ++mt)
#pragma unroll
      for (int r = 0; r < 4; ++r)
        *(unsigned short*)(smem + H1_OFF + mt * 4096 + r * 16 + hconst) = hb[mt][r];
  }
  __syncthreads();     // final h1 visible for epilogue

  // ================= epilogue: out[s][o] = h1 . wout[o] + bout[o] =========
  if (tid < 320) {
    int s = tid / 10, o = tid - (tid / 10) * 10;
    float sum = bout[o];
#pragma unroll
    for (int kc = 0; kc < 4; ++kc)
#pragma unroll
      for (int sb = 0; sb < 4; ++sb) {
        short8 hv = H1f[((s >> 4) * 4 + kc) * 64 + sb * 16 + (s & 15)];
        int dbase = kc * 32 + sb * 8;
        float4_t w0 = *(const float4_t*)(wout + o * 128 + dbase);
        float4_t w1 = *(const float4_t*)(wout + o * 128 + dbase + 4);
#pragma unroll
        for (int j = 0; j < 4; ++j) {
          sum += bf2f((unsigned short)hv[j])     * w0[j];
          sum += bf2f((unsigned short)hv[j + 4]) * w1[j];
        }
      }
    out[(size_t)(n0 + s) * 10 + o] = sum;
  }
}

extern "C" void kernel_launch(void* const* d_in, const int* in_sizes, int n_in,
                              void* d_out, int out_size, void* d_ws, size_t ws_size,
                              hipStream_t stream) {
  const float* x    = (const float*)d_in[0];
  const float* wih0 = (const float*)d_in[1];
  const float* whh0 = (const float*)d_in[2];
  const float* bih0 = (const float*)d_in[3];
  const float* bhh0 = (const float*)d_in[4];
  const float* wih1 = (const float*)d_in[5];
  const float* whh1 = (const float*)d_in[6];
  const float* bih1 = (const float*)d_in[7];
  const float* bhh1 = (const float*)d_in[8];
  const float* wout = (const float*)d_in[9];
  const float* bout = (const float*)d_in[10];

  unsigned short* wp = (unsigned short*)d_ws;   // 425984 B used

  pack_weights<<<832, 256, 0, stream>>>(wih0, whh0, wih1, whh1, wp);
  lstm_fused<<<256, 512, 0, stream>>>(x, wp, bih0, bhh0, bih1, bhh1, wout, bout,
                                      (float*)d_out);
}